// Round 7
// baseline (2908.283 us; speedup 1.0000x reference)
//
#include <hip/hip_runtime.h>

// Problem constants (fixed by the reference)
#define NN 20000      // nodes
#define EE 240000     // real edges
#define ETOTAL 260000 // edges + self loops
#define DIN 768
#define DD 256
#define NT 9          // tags
// heads = 4, DH = 64

typedef __attribute__((ext_vector_type(2))) float f32x2;

__device__ __forceinline__ float gelu_f(float x) {
  return 0.5f * x * (1.0f + erff(x * 0.70710678118654752440f));
}

// One Viterbi recurrence step (bitwise-exact). Measured model (r0-r2):
// step cost ~= 62 cyc fixed dependency chain + ~2.9 cyc/instr. Structurally
// minimal for an exact 9-state step; exact time-parallelization ruled out
// (boundary-stitch fp perturbation -> path flips). ~1.1 ms floor; unchanged.
#define VSTEP_CORE(EIN, SIN, SOUT)                                        \
  asm volatile(                                                           \
    "s_nop 2\n\t"                                                         \
    "v_readlane_b32 s84, %[sv], 0\n\t"                                    \
    "v_readlane_b32 s85, %[sv], 1\n\t"                                    \
    "v_readlane_b32 s86, %[sv], 2\n\t"                                    \
    "v_readlane_b32 s87, %[sv], 3\n\t"                                    \
    "v_readlane_b32 s88, %[sv], 4\n\t"                                    \
    "v_readlane_b32 s89, %[sv], 5\n\t"                                    \
    "v_readlane_b32 s90, %[sv], 6\n\t"                                    \
    "v_readlane_b32 s91, %[sv], 7\n\t"                                    \
    "v_readlane_b32 s92, %[sv], 8\n\t"                                    \
    "v_pk_add_f32 v[80:81], s[84:85], %[u01]\n\t"                         \
    "v_pk_add_f32 v[82:83], s[86:87], %[u23]\n\t"                         \
    "v_pk_add_f32 v[84:85], s[88:89], %[u45]\n\t"                         \
    "v_pk_add_f32 v[86:87], s[90:91], %[u67]\n\t"                         \
    "v_add_f32 v88, s92, %[u8]\n\t"                                       \
    "v_max3_f32 v80, v80, v81, v82\n\t"                                   \
    "v_max3_f32 v83, v83, v84, v85\n\t"                                   \
    "v_max3_f32 v86, v86, v87, v88\n\t"                                   \
    "v_max3_f32 v80, v80, v83, v86\n\t"                                   \
    "v_add_f32 %[out], v80, %[e]\n\t"                                     \
    : [out]"=v"(SOUT)                                                     \
    : [sv]"v"(SIN), [e]"v"(EIN),                                          \
      [u01]"v"(tc01), [u23]"v"(tc23), [u45]"v"(tc45), [u67]"v"(tc67),     \
      [u8]"v"(tcol8)                                                      \
    : "s84","s85","s86","s87","s88","s89","s90","s91","s92",              \
      "v80","v81","v82","v83","v84","v85","v86","v87","v88")

// 8 steps; sv layout packs 4 consecutive steps of one lane into one float4
// (sv[(t>>2)*256 + lane*4 + (t&3)]) -> one dwordx4 store per 4 steps.
#define RUN8(E0, E1) do {                                                 \
  float s0, s1, s2, s3, s4, s5, s6, s7;                                   \
  VSTEP_CORE((E0).x, s, s0); VSTEP_CORE((E0).y, s0, s1);                  \
  VSTEP_CORE((E0).z, s1, s2); VSTEP_CORE((E0).w, s2, s3);                 \
  float4 stq0; stq0.x = s0; stq0.y = s1; stq0.z = s2; stq0.w = s3;        \
  *(float4*)svp = stq0;                                                   \
  VSTEP_CORE((E1).x, s3, s4); VSTEP_CORE((E1).y, s4, s5);                 \
  VSTEP_CORE((E1).z, s5, s6); VSTEP_CORE((E1).w, s6, s7);                 \
  float4 stq1; stq1.x = s4; stq1.y = s5; stq1.z = s6; stq1.w = s7;        \
  *(float4*)(svp + 256) = stq1;                                           \
  s = s7; svp += 512;                                                     \
} while (0)

// ---------------- GEMM: C = act(A@B + bias) ----------------
// A: MxK row-major, B: KxN row-major, C: MxN. Requires N%64==0, K%32==0.
// act: 0 = none, 1 = gelu, 2 = bn(g,b) then relu
// 64x64 tile, 4x4/thread, DOUBLE-BUFFERED LDS with register staging:
// issue next tile's global loads -> compute current from LDS[buf] ->
// write regs to LDS[buf^1] -> ONE barrier. Global latency hides under the
// compute phase; barriers/tile halved. LDS 32KB -> 5 blocks/CU, >= the 4.9
// resident at grid 1252 (grid unchanged — the r3 lesson). Accumulation
// k-order unchanged -> outputs bitwise identical.
__global__ __launch_bounds__(256) void gemm_k(
    const float* __restrict__ A, const float* __restrict__ B,
    const float* __restrict__ bias,
    const float* __restrict__ bng, const float* __restrict__ bnb,
    float* __restrict__ C, int M, int K, int N, int act)
{
  __shared__ float As[2][32][64];   // transposed A tile: As[b][k][m]
  __shared__ float Bs[2][32][64];   // Bs[b][k][n]
  const int tid = threadIdx.x;
  const int tx = tid & 15, ty = tid >> 4;
  const int m0 = blockIdx.y * 64, n0 = blockIdx.x * 64;
  // staging slots: A rows rA0/rA0+32 (col group cA0), B rows rB0/rB0+16
  const int rA0 = tid >> 3, cA0 = tid & 7;
  const int rB0 = tid >> 4, cB0 = tid & 15;
  const int gmA0 = m0 + rA0, gmA1 = m0 + rA0 + 32;
  float4 a0, a1, b0, b1;
  float acc[4][4];
#pragma unroll
  for (int i = 0; i < 4; ++i)
#pragma unroll
    for (int j = 0; j < 4; ++j) acc[i][j] = 0.f;

#define G_LOAD(kk) do {                                                     \
    a0 = make_float4(0.f, 0.f, 0.f, 0.f); a1 = a0;                          \
    if (gmA0 < M) a0 = *(const float4*)(A + (size_t)gmA0 * K + (kk) + cA0 * 4); \
    if (gmA1 < M) a1 = *(const float4*)(A + (size_t)gmA1 * K + (kk) + cA0 * 4); \
    b0 = *(const float4*)(B + (size_t)((kk) + rB0) * N + n0 + cB0 * 4);     \
    b1 = *(const float4*)(B + (size_t)((kk) + rB0 + 16) * N + n0 + cB0 * 4);\
  } while (0)
#define L_WRITE(bf) do {                                                    \
    As[bf][cA0 * 4 + 0][rA0] = a0.x; As[bf][cA0 * 4 + 1][rA0] = a0.y;       \
    As[bf][cA0 * 4 + 2][rA0] = a0.z; As[bf][cA0 * 4 + 3][rA0] = a0.w;       \
    As[bf][cA0 * 4 + 0][rA0 + 32] = a1.x; As[bf][cA0 * 4 + 1][rA0 + 32] = a1.y; \
    As[bf][cA0 * 4 + 2][rA0 + 32] = a1.z; As[bf][cA0 * 4 + 3][rA0 + 32] = a1.w; \
    *(float4*)&Bs[bf][rB0][cB0 * 4] = b0;                                   \
    *(float4*)&Bs[bf][rB0 + 16][cB0 * 4] = b1;                              \
  } while (0)
#define COMPUTE(bf) do {                                                    \
    _Pragma("unroll")                                                       \
    for (int k = 0; k < 32; ++k) {                                          \
      float a[4], b[4];                                                     \
      *(float4*)a = *(const float4*)&As[bf][k][ty * 4];                     \
      *(float4*)b = *(const float4*)&Bs[bf][k][tx * 4];                     \
      _Pragma("unroll")                                                     \
      for (int i = 0; i < 4; ++i)                                           \
        _Pragma("unroll")                                                   \
        for (int j = 0; j < 4; ++j) acc[i][j] += a[i] * b[j];               \
    }                                                                       \
  } while (0)

  G_LOAD(0); L_WRITE(0); __syncthreads();
  int buf = 0;
  for (int kk = 32; kk < K; kk += 32) {
    G_LOAD(kk);            // issue next tile loads (latency overlaps compute)
    COMPUTE(buf);
    L_WRITE(buf ^ 1);      // waits on loads here, after compute
    __syncthreads();
    buf ^= 1;
  }
  COMPUTE(buf);
#undef G_LOAD
#undef L_WRITE
#undef COMPUTE

  const float bnc = 0.99999500003749968752f;  // 1/sqrt(1+1e-5)
#pragma unroll
  for (int i = 0; i < 4; ++i) {
    int gm = m0 + ty * 4 + i;
    if (gm >= M) continue;
    float o[4];
#pragma unroll
    for (int j = 0; j < 4; ++j) {
      int n = n0 + tx * 4 + j;
      float x = acc[i][j];
      if (bias) x += bias[n];
      if (act == 1) x = gelu_f(x);
      else if (act == 2) { x = x * (bng[n] * bnc) + bnb[n]; x = fmaxf(x, 0.f); }
      o[j] = x;
    }
    *(float4*)(C + (size_t)gm * N + n0 + tx * 4) = *(const float4*)o;
  }
}

// ---------------- fused Q/K/M projections (shared A, 3 B's) ----------------
// C0 = A@B0 + bias0 ; C1 = A@B1 ; C2 = A@B2. K = N = 256 fixed.
// Single-buffered: doubling its 32KB LDS would cap at 2 blocks/CU (r3
// failure mode). A-tile already amortized over 3 GEMMs (12:1 fma:ds).
__global__ __launch_bounds__(256) void gemm3_k(
    const float* __restrict__ A, const float* __restrict__ B0,
    const float* __restrict__ bias0, const float* __restrict__ B1,
    const float* __restrict__ B2, float* __restrict__ C0,
    float* __restrict__ C1, float* __restrict__ C2, int M)
{
  __shared__ float As[32][64];
  __shared__ float Bs[3][32][64];
  const int tid = threadIdx.x;
  const int tx = tid & 15, ty = tid >> 4;
  const int m0 = blockIdx.y * 64, n0 = blockIdx.x * 64;
  float acc0[4][4], acc1[4][4], acc2[4][4];
#pragma unroll
  for (int i = 0; i < 4; ++i)
#pragma unroll
    for (int j = 0; j < 4; ++j) { acc0[i][j] = 0.f; acc1[i][j] = 0.f; acc2[i][j] = 0.f; }

  for (int kk = 0; kk < DD; kk += 32) {
#pragma unroll
    for (int L = tid; L < 512; L += 256) {   // A tile: 64 rows x 8 float4
      int r = L >> 3, c4 = L & 7;
      int gm = m0 + r;
      float4 v = make_float4(0.f, 0.f, 0.f, 0.f);
      if (gm < M) v = *(const float4*)(A + (size_t)gm * DD + kk + c4 * 4);
      As[c4 * 4 + 0][r] = v.x; As[c4 * 4 + 1][r] = v.y;
      As[c4 * 4 + 2][r] = v.z; As[c4 * 4 + 3][r] = v.w;
    }
#pragma unroll
    for (int L = tid; L < 1536; L += 256) {  // 3 B tiles: 32 rows x 16 float4
      int which = L >> 9, r = (L >> 4) & 31, c4 = L & 15;
      const float* Bp = (which == 0) ? B0 : (which == 1) ? B1 : B2;
      *(float4*)&Bs[which][r][c4 * 4] =
          *(const float4*)(Bp + (size_t)(kk + r) * DD + n0 + c4 * 4);
    }
    __syncthreads();
#pragma unroll
    for (int k = 0; k < 32; ++k) {
      float a[4], b0[4], b1[4], b2[4];
      *(float4*)a = *(const float4*)&As[k][ty * 4];
      *(float4*)b0 = *(const float4*)&Bs[0][k][tx * 4];
      *(float4*)b1 = *(const float4*)&Bs[1][k][tx * 4];
      *(float4*)b2 = *(const float4*)&Bs[2][k][tx * 4];
#pragma unroll
      for (int i = 0; i < 4; ++i)
#pragma unroll
        for (int j = 0; j < 4; ++j) {
          acc0[i][j] += a[i] * b0[j];
          acc1[i][j] += a[i] * b1[j];
          acc2[i][j] += a[i] * b2[j];
        }
    }
    __syncthreads();
  }
#pragma unroll
  for (int i = 0; i < 4; ++i) {
    int gm = m0 + ty * 4 + i;
    if (gm >= M) continue;
    float o0[4], o1[4], o2[4];
#pragma unroll
    for (int j = 0; j < 4; ++j) {
      int n = n0 + tx * 4 + j;
      o0[j] = acc0[i][j] + bias0[n];
      o1[j] = acc1[i][j];
      o2[j] = acc2[i][j];
    }
    *(float4*)(C0 + (size_t)gm * DD + n0 + tx * 4) = *(const float4*)o0;
    *(float4*)(C1 + (size_t)gm * DD + n0 + tx * 4) = *(const float4*)o1;
    *(float4*)(C2 + (size_t)gm * DD + n0 + tx * 4) = *(const float4*)o2;
  }
}

// ---------------- fused two-segment GEMM: C = gelu(A1@B1 + A2@B2 + b1 + b2) -
// K = 256 per segment, N = 256 fixed. 64x64 tile, double-buffered (see gemm_k).
__global__ __launch_bounds__(256) void gemm_cat_k(
    const float* __restrict__ A1, const float* __restrict__ B1,
    const float* __restrict__ bias1, const float* __restrict__ A2,
    const float* __restrict__ B2, const float* __restrict__ bias2,
    float* __restrict__ C, int M)
{
  __shared__ float As[2][32][64];
  __shared__ float Bs[2][32][64];
  const int tid = threadIdx.x;
  const int tx = tid & 15, ty = tid >> 4;
  const int m0 = blockIdx.y * 64, n0 = blockIdx.x * 64;
  const int rA0 = tid >> 3, cA0 = tid & 7;
  const int rB0 = tid >> 4, cB0 = tid & 15;
  const int gmA0 = m0 + rA0, gmA1 = m0 + rA0 + 32;
  float4 a0, a1, b0, b1;
  float acc[4][4];
#pragma unroll
  for (int i = 0; i < 4; ++i)
#pragma unroll
    for (int j = 0; j < 4; ++j) acc[i][j] = 0.f;

#define G_LOAD(kk) do {                                                     \
    const float* Ap = ((kk) < DD) ? A1 : A2;                                \
    const float* Bp = ((kk) < DD) ? B1 : B2;                                \
    const int ko = (kk) & (DD - 1);                                         \
    a0 = make_float4(0.f, 0.f, 0.f, 0.f); a1 = a0;                          \
    if (gmA0 < M) a0 = *(const float4*)(Ap + (size_t)gmA0 * DD + ko + cA0 * 4); \
    if (gmA1 < M) a1 = *(const float4*)(Ap + (size_t)gmA1 * DD + ko + cA0 * 4); \
    b0 = *(const float4*)(Bp + (size_t)(ko + rB0) * DD + n0 + cB0 * 4);     \
    b1 = *(const float4*)(Bp + (size_t)(ko + rB0 + 16) * DD + n0 + cB0 * 4);\
  } while (0)
#define L_WRITE(bf) do {                                                    \
    As[bf][cA0 * 4 + 0][rA0] = a0.x; As[bf][cA0 * 4 + 1][rA0] = a0.y;       \
    As[bf][cA0 * 4 + 2][rA0] = a0.z; As[bf][cA0 * 4 + 3][rA0] = a0.w;       \
    As[bf][cA0 * 4 + 0][rA0 + 32] = a1.x; As[bf][cA0 * 4 + 1][rA0 + 32] = a1.y; \
    As[bf][cA0 * 4 + 2][rA0 + 32] = a1.z; As[bf][cA0 * 4 + 3][rA0 + 32] = a1.w; \
    *(float4*)&Bs[bf][rB0][cB0 * 4] = b0;                                   \
    *(float4*)&Bs[bf][rB0 + 16][cB0 * 4] = b1;                              \
  } while (0)
#define COMPUTE(bf) do {                                                    \
    _Pragma("unroll")                                                       \
    for (int k = 0; k < 32; ++k) {                                          \
      float a[4], b[4];                                                     \
      *(float4*)a = *(const float4*)&As[bf][k][ty * 4];                     \
      *(float4*)b = *(const float4*)&Bs[bf][k][tx * 4];                     \
      _Pragma("unroll")                                                     \
      for (int i = 0; i < 4; ++i)                                           \
        _Pragma("unroll")                                                   \
        for (int j = 0; j < 4; ++j) acc[i][j] += a[i] * b[j];               \
    }                                                                       \
  } while (0)

  G_LOAD(0); L_WRITE(0); __syncthreads();
  int buf = 0;
  for (int kk = 32; kk < 2 * DD; kk += 32) {
    G_LOAD(kk);
    COMPUTE(buf);
    L_WRITE(buf ^ 1);
    __syncthreads();
    buf ^= 1;
  }
  COMPUTE(buf);
#undef G_LOAD
#undef L_WRITE
#undef COMPUTE

#pragma unroll
  for (int i = 0; i < 4; ++i) {
    int gm = m0 + ty * 4 + i;
    if (gm >= M) continue;
    float o[4];
#pragma unroll
    for (int j = 0; j < 4; ++j) {
      int n = n0 + tx * 4 + j;
      o[j] = gelu_f(acc[i][j] + bias1[n] + bias2[n]);
    }
    *(float4*)(C + (size_t)gm * DD + n0 + tx * 4) = *(const float4*)o;
  }
}

// ---------------- per-layer edge-type tables, all 3 layers batched ---------
// 27 blocks (layer = blockIdx/NT, type = blockIdx%NT); weights-only
// dependency -> hoisted out of the layer loop (one launch instead of three).
__global__ __launch_bounds__(256) void edge_tables3_k(
    const float* __restrict__ We1, const float* __restrict__ be1,
    const float* __restrict__ g1, const float* __restrict__ bb1,
    const float* __restrict__ We2, const float* __restrict__ be2,
    const float* __restrict__ Wk, const float* __restrict__ bk,
    const float* __restrict__ Wm, const float* __restrict__ bm,
    float* __restrict__ ketab3, float* __restrict__ metab3)
{
  __shared__ float r_s[DD];
  __shared__ float e_s[DD];
  const int l = blockIdx.x / NT, t = blockIdx.x - l * NT, d = threadIdx.x;
  const float* We1l = We1 + (size_t)l * NT * DD;
  const float* We2l = We2 + (size_t)l * DD * DD;
  const float* WkEl = Wk + (size_t)l * 2 * DD * DD + DD * DD;
  const float* WmEl = Wm + (size_t)l * 2 * DD * DD + DD * DD;
  const float bnc = 0.99999500003749968752f;
  float pre = We1l[t * DD + d] + be1[l * DD + d];
  float bnv = pre * (g1[l * DD + d] * bnc) + bb1[l * DD + d];
  r_s[d] = fmaxf(bnv, 0.f);
  __syncthreads();
  float acc = 0.f;
  for (int c = 0; c < DD; ++c) acc += r_s[c] * We2l[c * DD + d];
  e_s[d] = acc + be2[l * DD + d];
  __syncthreads();
  float ka = 0.f, ma = 0.f;
  for (int c = 0; c < DD; ++c) {
    float ec = e_s[c];
    ka += ec * WkEl[c * DD + d];
    ma += ec * WmEl[c * DD + d];
  }
  ketab3[(size_t)l * NT * DD + t * DD + d] = ka + bk[l * DD + d];
  metab3[(size_t)l * NT * DD + t * DD + d] = ma + bm[l * DD + d];
}

// ---------------- degree counts ----------------
__global__ void deg_k(const int* __restrict__ ei, int* __restrict__ cnt,
                      int* __restrict__ cnt_d)
{
  for (int e = blockIdx.x * blockDim.x + threadIdx.x; e < EE; e += gridDim.x * blockDim.x) {
    atomicAdd(&cnt[ei[e]], 1);        // src out-degree (real edges)
    atomicAdd(&cnt_d[ei[EE + e]], 1); // dst in-degree (real edges)
  }
}

// ---------------- exclusive scan (single block, generic input) -------------
__global__ __launch_bounds__(256) void scan_k(const int* __restrict__ c,
                                              int* __restrict__ offs)
{
  __shared__ int part[257];
  const int tid = threadIdx.x;
  const int CH = (NN + 255) / 256;
  int a = tid * CH, b = a + CH; if (b > NN) b = NN;
  int s = 0;
  for (int i = a; i < b; ++i) s += c[i];
  part[tid] = s;
  __syncthreads();
  if (tid == 0) {
    int r = 0;
    for (int i = 0; i < 256; ++i) { int v = part[i]; part[i] = r; r += v; }
    part[256] = r;
  }
  __syncthreads();
  int r = part[tid];
  for (int i = a; i < b; ++i) { offs[i] = r; r += c[i]; }
  if (tid == 255) offs[NN] = part[256];
}

// ---------------- CSR fill (generic key array) ----------------
__global__ void fill_k(const int* __restrict__ key, const int* __restrict__ offs,
                       int* __restrict__ fc, int* __restrict__ eix)
{
  for (int e = blockIdx.x * blockDim.x + threadIdx.x; e < EE; e += gridDim.x * blockDim.x) {
    int d = key[e];
    int p = offs[d] + atomicAdd(&fc[d], 1);
    eix[p] = e;
  }
}

// ---------------- pack CSR payloads: {other-node, (e<<4)|type} -------------
// Flattens the eix->ei->et dependent-load chains in score2/aggr2 to a single
// 8B load per edge (e < 2^18, t < 16).
__global__ void pack_k(const int* __restrict__ ei, const int* __restrict__ et,
                       const int* __restrict__ eix, const int* __restrict__ eix_s,
                       int2* __restrict__ srcte_d, int2* __restrict__ dstte_s)
{
  for (int o = blockIdx.x * blockDim.x + threadIdx.x; o < EE; o += gridDim.x * blockDim.x) {
    int e = eix[o];                       // dst-CSR slot o
    srcte_d[o] = make_int2(ei[e], (e << 4) | et[e]);
    int e2 = eix_s[o];                    // src-CSR slot o
    dstte_s[o] = make_int2(ei[EE + e2], (e2 << 4) | et[e2]);
  }
}

// ---------------- fused scores + softmax stats (wave per src) --------------
// Q row loaded ONCE per src. Dot expression q·(k+ke), shuffle order, and
// *0.125 are IDENTICAL to the original score_k -> sbuf and the segment max
// are bitwise unchanged. The denominator uses an online running-max sum
// (order perturbation ~1e-7 — empirically validated by r4's atomic->tree
// den change, path bit-identical).
__global__ __launch_bounds__(256) void score2_k(
    const float* __restrict__ Q, const float* __restrict__ Kn,
    const float* __restrict__ ketab, const int* __restrict__ offs_s,
    const int2* __restrict__ dstte_s, float* __restrict__ sbuf,
    float2* __restrict__ sd)
{
  __shared__ float ke_s[NT * DD];
  for (int i = threadIdx.x; i < NT * DD; i += 256) ke_s[i] = ketab[i];
  __syncthreads();
  const int lane = threadIdx.x & 63, wave = threadIdx.x >> 6;
  const int h = lane >> 4, sl = lane & 15;
  const float4* Q4 = (const float4*)Q;
  const float4* K4 = (const float4*)Kn;
  int src = blockIdx.x * 4 + wave;
  if (src >= NN) return;
  float4 q = Q4[src * 64 + lane];
  float mx, sum;
  {
    // self-loop (edge id EE+src, type NT-1), k row = K[src]
    float4 k = K4[src * 64 + lane];
    float4 ke = *(const float4*)(ke_s + (NT - 1) * DD + lane * 4);
    float p = q.x * (k.x + ke.x) + q.y * (k.y + ke.y) +
              q.z * (k.z + ke.z) + q.w * (k.w + ke.w);
    p += __shfl_xor(p, 8); p += __shfl_xor(p, 4);
    p += __shfl_xor(p, 2); p += __shfl_xor(p, 1);
    float se = p * 0.125f;
    if (sl == 0) sbuf[(EE + src) * 4 + h] = se;
    mx = se; sum = 1.0f;                 // expf(se-se)=1 exactly
  }
  int o1 = offs_s[src + 1];
  for (int o = offs_s[src]; o < o1; ++o) {
    int2 dt = dstte_s[o];
    int dst = dt.x, e = dt.y >> 4, t = dt.y & 15;
    float4 k = K4[dst * 64 + lane];
    float4 ke = *(const float4*)(ke_s + t * DD + lane * 4);
    float p = q.x * (k.x + ke.x) + q.y * (k.y + ke.y) +
              q.z * (k.z + ke.z) + q.w * (k.w + ke.w);
    p += __shfl_xor(p, 8); p += __shfl_xor(p, 4);
    p += __shfl_xor(p, 2); p += __shfl_xor(p, 1);
    float se = p * 0.125f;
    if (sl == 0) sbuf[e * 4 + h] = se;
    float nm = fmaxf(mx, se);            // final mx bitwise = old atomicMax
    sum = sum * expf(mx - nm) + expf(se - nm);  // exp(0)=1 exact
    mx = nm;
  }
  if (sl == 0) sd[src * 4 + h] = make_float2(mx, sum);
}

// ---------------- pass C: atomic-free aggregation (wave per dst) -----------
// alpha computed inline from raw scores + packed {max,den}; per-edge payload
// from the packed dst-CSR (single 8B load, no eix->ei->et chain).
__global__ __launch_bounds__(256) void aggr2_k(
    const float* __restrict__ Mn, const float* __restrict__ metab,
    const float* __restrict__ sbuf, const float2* __restrict__ sd,
    const int* __restrict__ cnt, const int* __restrict__ offs,
    const int2* __restrict__ srcte_d, float* __restrict__ aggr)
{
  __shared__ float me_s[NT * DD];
  for (int i = threadIdx.x; i < NT * DD; i += 256) me_s[i] = metab[i];
  __syncthreads();
  const int lane = threadIdx.x & 63, wave = threadIdx.x >> 6;
  const int h = lane >> 4;
  const float4* M4 = (const float4*)Mn;
  int dst = blockIdx.x * 4 + wave;
  if (dst >= NN) return;
  float4 acc;
  {
    // self-loop (edge id EE+dst, type NT-1)
    float2 sdv = sd[dst * 4 + h];
    float ex = expf(sbuf[(EE + dst) * 4 + h] - sdv.x);
    float alpha = ex / (sdv.y + 1e-16f) * (float)(cnt[dst] + 1);
    float4 m = M4[dst * 64 + lane];
    float4 me = *(const float4*)(me_s + (NT - 1) * DD + lane * 4);
    acc.x = (m.x + me.x) * alpha; acc.y = (m.y + me.y) * alpha;
    acc.z = (m.z + me.z) * alpha; acc.w = (m.w + me.w) * alpha;
  }
  int o1 = offs[dst + 1];
  for (int o = offs[dst]; o < o1; ++o) {
    int2 st = srcte_d[o];
    int src = st.x, e = st.y >> 4, t = st.y & 15;
    float2 sdv = sd[src * 4 + h];
    float ex = expf(sbuf[e * 4 + h] - sdv.x);
    float alpha = ex / (sdv.y + 1e-16f) * (float)(cnt[src] + 1);
    float4 m = M4[src * 64 + lane];
    float4 me = *(const float4*)(me_s + t * DD + lane * 4);
    acc.x += (m.x + me.x) * alpha; acc.y += (m.y + me.y) * alpha;
    acc.z += (m.z + me.z) * alpha; acc.w += (m.w + me.w) * alpha;
  }
  ((float4*)aggr)[dst * 64 + lane] = acc;
}

// ---------------- emissions: em = hidden @ Wt + bt  (256 -> 9) -------------
__global__ __launch_bounds__(256) void emis_k(
    const float* __restrict__ hidden, const float* __restrict__ Wt,
    const float* __restrict__ bt, float* __restrict__ em)
{
  __shared__ float wt_s[DD * NT];
  for (int i = threadIdx.x; i < DD * NT; i += 256) wt_s[i] = Wt[i];
  __syncthreads();
  const int lane = threadIdx.x & 63, wave = threadIdx.x >> 6;
  const float4* H4 = (const float4*)hidden;
  for (int n = blockIdx.x * 4 + wave; n < NN; n += gridDim.x * 4) {
    float4 h = H4[n * 64 + lane];
    const float* w0 = wt_s + (lane * 4) * NT;
    float p[NT];
#pragma unroll
    for (int t = 0; t < NT; ++t)
      p[t] = h.x * w0[t] + h.y * w0[NT + t] + h.z * w0[2 * NT + t] + h.w * w0[3 * NT + t];
#pragma unroll
    for (int m = 32; m >= 1; m >>= 1)
#pragma unroll
      for (int t = 0; t < NT; ++t) p[t] += __shfl_xor(p[t], m);
    if (lane == 0) {
#pragma unroll
      for (int t = 0; t < NT; ++t) em[n * NT + t] = p[t] + bt[t];
    }
  }
}

// ---------------- Viterbi decode (single block) ----------------------------
// Forward scan: wave0, lanes replicate states j=min(lane&15,8). Recurrence =
// VSTEP_CORE asm (readlane into SGPR pairs + 4 pk_add + exact max3 tree ->
// bitwise identical). Emissions staged TRANSPOSED in LDS (embufT[j][t],
// padded row stride 524): one ds_read_b128 delivers 4 steps; double-buffered
// one 8-step group ahead. Score rows stored quad-packed:
// sv[(t>>2)*256 + lane*4 + (t&3)] -> one dwordx4 store per 4 steps.
// Backpointers recomputed bitwise-exactly in the parallel backtrack
// (first-index tie rule = jnp.argmax).
__global__ __launch_bounds__(256) void viterbi_k(
    const float* __restrict__ em, const float* __restrict__ cstart,
    const float* __restrict__ cend, const float* __restrict__ ctrans,
    float* __restrict__ sv, int* __restrict__ outp)
{
  const int VCS = 512;
  const int ST = VCS + 12;        // 524 floats: 524%32=12 -> 9 rows spread banks
  const int NCH = (NN + VCS - 1) / VCS;
  __shared__ float embufT[2][NT][VCS + 12];
  __shared__ float trT[NT * 16];              // trT[j*16+i] = trans[i][j]
  __shared__ float scf[NT];
  __shared__ unsigned char fmaps[256][NT];
  __shared__ unsigned char ends_s[256];
  __shared__ int last_s;
  const int tid = threadIdx.x, lane = tid & 63, wave = tid >> 6;
  const int jl = min(lane & 15, NT - 1);

  for (int i = tid; i < VCS * NT; i += 256) {   // chunk 0, transposed
    int t = i / NT, j = i - t * NT;
    embufT[0][j][t] = em[i];
  }
  if (tid < NT * NT) trT[(tid % NT) * 16 + (tid / NT)] = ctrans[tid];
  __syncthreads();

  f32x2 tc01, tc23, tc45, tc67;   // tcol[i] = trans[i][jl], packed in pairs
  float tcol8 = 0.f;
  float s = 0.f;
  if (wave == 0) {
    tc01[0] = ctrans[0 * NT + jl]; tc01[1] = ctrans[1 * NT + jl];
    tc23[0] = ctrans[2 * NT + jl]; tc23[1] = ctrans[3 * NT + jl];
    tc45[0] = ctrans[4 * NT + jl]; tc45[1] = ctrans[5 * NT + jl];
    tc67[0] = ctrans[6 * NT + jl]; tc67[1] = ctrans[7 * NT + jl];
    tcol8   = ctrans[8 * NT + jl];
    s = cstart[jl] + embufT[0][jl][0];
    sv[lane * 4] = s;             // row t=0: quad 0, slot 0
  }

  for (int c = 0; c < NCH; ++c) {
    if (wave > 0) {
      if (c + 1 < NCH) {
        int base = (c + 1) * VCS * NT;
        int n2 = VCS * NT;
        if (base + n2 > NN * NT) n2 = NN * NT - base;
        float* dstb = &embufT[(c + 1) & 1][0][0];
        for (int i = tid - 64; i < n2; i += 192) {
          int t = i / NT, j = i - t * NT;
          dstb[j * ST + t] = em[base + i];
        }
      }
    } else {
      const float* ebT = &embufT[c & 1][0][0] + (size_t)jl * ST;
      int tbeg = (c == 0) ? 1 : c * VCS;
      int tend = (c + 1) * VCS; if (tend > NN) tend = NN;
      int off = tbeg - c * VCS;
      int nsteps = tend - tbeg;
      // scalar head: align t to a multiple of 8
      int pre = (8 - (tbeg & 7)) & 7; if (pre > nsteps) pre = nsteps;
      for (int i = 0; i < pre; ++i) {
        int t = tbeg + i;
        float e0 = ebT[off + i];
        float so;
        VSTEP_CORE(e0, s, so);
        s = so;
        sv[((size_t)t >> 2) * 256 + lane * 4 + (t & 3)] = s;
      }
      int rem = nsteps - pre;
      int ngr = rem >> 3;
      int tof = off + pre;                     // 16B-aligned (0 or 8)
      float* svp = sv + ((size_t)(tbeg + pre) >> 2) * 256 + lane * 4;
      if (ngr > 0) {
        float4 eA0 = *(const float4*)&ebT[tof];
        float4 eA1 = *(const float4*)&ebT[tof + 4];
        float4 eB0, eB1;
        int g = 0;
        while (g + 2 <= ngr) {
          eB0 = *(const float4*)&ebT[tof + (g + 1) * 8];
          eB1 = *(const float4*)&ebT[tof + (g + 1) * 8 + 4];
          RUN8(eA0, eA1);
          eA0 = *(const float4*)&ebT[tof + (g + 2) * 8];     // pad overread ok
          eA1 = *(const float4*)&ebT[tof + (g + 2) * 8 + 4];
          RUN8(eB0, eB1);
          g += 2;
        }
        if (g < ngr) RUN8(eA0, eA1);
      }
      // scalar tail (rem % 8 steps; 0 for this problem size but kept generic)
      for (int i = pre + (ngr << 3); i < nsteps; ++i) {
        int t = tbeg + i;
        float e0 = ebT[off + i];
        float so;
        VSTEP_CORE(e0, s, so);
        s = so;
        sv[((size_t)t >> 2) * 256 + lane * 4 + (t & 3)] = s;
      }
    }
    __syncthreads();
  }

  if (wave == 0 && lane < NT) scf[lane] = s + cend[lane];
  __syncthreads();
  if (tid == 0) {
    float bv = scf[0]; int bi = 0;
    for (int j = 1; j < NT; ++j) if (scf[j] > bv) { bv = scf[j]; bi = j; }
    last_s = bi;
  }
  __syncthreads();

  // backtrack: per-range end->start maps via exact bp recomputation
  // sv row t, state i lives at sv[(t>>2)*256 + i*4 + (t&3)]
  const int RL = 79;
  int a = 1 + tid * RL;
  int b = a + RL; if (b > NN) b = NN;
  bool active = (a < NN);
  if (active) {
    int x[NT];
#pragma unroll
    for (int j = 0; j < NT; ++j) x[j] = j;
    for (int t = b - 1; t >= a; --t) {
      const float* sp = sv + ((size_t)(t - 1) >> 2) * 256 + ((t - 1) & 3);
      float sr[NT];
#pragma unroll
      for (int i = 0; i < NT; ++i) sr[i] = sp[i * 4];
#pragma unroll
      for (int j = 0; j < NT; ++j) {
        const float* tcx = trT + x[j] * 16;
        float bv = sr[0] + tcx[0]; int bi = 0;
#pragma unroll
        for (int i = 1; i < NT; ++i) {
          float cv = sr[i] + tcx[i];
          if (cv > bv) { bv = cv; bi = i; }
        }
        x[j] = bi;
      }
    }
#pragma unroll
    for (int j = 0; j < NT; ++j) fmaps[tid][j] = (unsigned char)x[j];
  }
  __syncthreads();
  if (tid == 0) {
    int x = last_s;
    for (int k = 255; k >= 0; --k) {
      ends_s[k] = (unsigned char)x;
      int ak = 1 + k * RL;
      if (ak < NN) x = fmaps[k][x];
    }
  }
  __syncthreads();
  if (active) {
    int x = ends_s[tid];
    outp[b - 1] = x;
    for (int t = b - 1; t >= a; --t) {
      const float* sp = sv + ((size_t)(t - 1) >> 2) * 256 + ((t - 1) & 3);
      const float* tcx = trT + x * 16;
      float bv = sp[0] + tcx[0]; int bi = 0;
#pragma unroll
      for (int i = 1; i < NT; ++i) {
        float cv = sp[i * 4] + tcx[i];
        if (cv > bv) { bv = cv; bi = i; }
      }
      x = bi;
      outp[t - 1] = x;
    }
  }
}

// ---------------------------------------------------------------------------
extern "C" void kernel_launch(void* const* d_in, const int* in_sizes, int n_in,
                              void* d_out, int out_size, void* d_ws, size_t ws_size,
                              hipStream_t stream)
{
  const float* node_emb = (const float*)d_in[0];
  const int* edge_index = (const int*)d_in[1];
  const int* edge_type = (const int*)d_in[2];
  // d_in[3] = tag_gt (unused by reference)
  const float* W_lm2gnn = (const float*)d_in[4];
  const float* b_lm2gnn = (const float*)d_in[5];
  const float* We1 = (const float*)d_in[6];
  const float* be1 = (const float*)d_in[7];
  const float* g1 = (const float*)d_in[8];
  const float* bb1 = (const float*)d_in[9];
  const float* We2 = (const float*)d_in[10];
  const float* be2 = (const float*)d_in[11];
  const float* Wq = (const float*)d_in[12];
  const float* bq = (const float*)d_in[13];
  const float* Wk = (const float*)d_in[14];
  const float* bk = (const float*)d_in[15];
  const float* Wm = (const float*)d_in[16];
  const float* bm = (const float*)d_in[17];
  const float* Wp1 = (const float*)d_in[18];
  const float* bp1 = (const float*)d_in[19];
  const float* g2 = (const float*)d_in[20];
  const float* bb2 = (const float*)d_in[21];
  const float* Wp2 = (const float*)d_in[22];
  const float* bp2 = (const float*)d_in[23];
  const float* Wo = (const float*)d_in[24];
  const float* bo = (const float*)d_in[25];
  const float* Wc = (const float*)d_in[26];
  const float* bc = (const float*)d_in[27];
  const float* Wt = (const float*)d_in[28];
  const float* bt = (const float*)d_in[29];
  const float* cstart = (const float*)d_in[30];
  const float* cend = (const float*)d_in[31];
  const float* ctrans = (const float*)d_in[32];

  // Workspace layout: 5 big node buffers + small region.
  const size_t NB = (size_t)NN * DD * sizeof(float); // 20,480,000
  char* w = (char*)d_ws;
  float* H0 = (float*)(w + 0 * NB);
  float* Xb = (float*)(w + 1 * NB);
  float* Qb = (float*)(w + 2 * NB);   // Q, then Xl, then hidden
  float* Kb = (float*)(w + 3 * NB);   // K, then aggr
  float* Mb = (float*)(w + 4 * NB);   // M
  char* sm = w + 5 * NB;
  size_t smo = 0;
  auto alloc = [&](size_t bytes) { char* p = sm + smo; smo += (bytes + 255) & ~255ull; return p; };
  float* sbuf = (float*)alloc((size_t)ETOTAL * 4 * 4);
  // zeroed-together region: cnt, cnt_d, offs, fc, offs_s, fc_s
  int* cnt = (int*)alloc((size_t)NN * 4);
  int* cnt_d = (int*)alloc((size_t)NN * 4);
  int* offs = (int*)alloc((size_t)(NN + 1) * 4);
  int* fc = (int*)alloc((size_t)NN * 4);
  int* offs_s = (int*)alloc((size_t)(NN + 1) * 4);
  int* fc_s = (int*)alloc((size_t)NN * 4);
  int* eix = (int*)alloc((size_t)EE * 4);     // dst-CSR edge ids
  int* eix_s = (int*)alloc((size_t)EE * 4);   // src-CSR edge ids
  int2* srcte_d = (int2*)alloc((size_t)EE * 8);  // packed dst-CSR payload
  int2* dstte_s = (int2*)alloc((size_t)EE * 8);  // packed src-CSR payload
  float2* sd = (float2*)alloc((size_t)NN * 4 * 8);  // packed {smax, den}
  float* ketab3 = (float*)alloc((size_t)3 * NT * DD * 4);
  float* metab3 = (float*)alloc((size_t)3 * NT * DD * 4);
  float* em = (float*)alloc((size_t)NN * NT * 4);
  float* sv = (float*)alloc(((size_t)NN * 64 + 256) * 4);  // quad-packed score rows
  const size_t needed = 5 * NB + smo;
  if (ws_size < needed) return;  // fail visibly rather than corrupt

  dim3 gg(DD / 64, (NN + 63) / 64);

  // degree counts + dst-CSR + src-CSR + packed payloads (structure constant)
  hipMemsetAsync(cnt, 0, (size_t)((char*)eix - (char*)cnt), stream);
  deg_k<<<1024, 256, 0, stream>>>(edge_index, cnt, cnt_d);
  scan_k<<<1, 256, 0, stream>>>(cnt_d, offs);
  scan_k<<<1, 256, 0, stream>>>(cnt, offs_s);
  fill_k<<<1024, 256, 0, stream>>>(edge_index + EE, offs, fc, eix);    // by dst
  fill_k<<<1024, 256, 0, stream>>>(edge_index, offs_s, fc_s, eix_s);   // by src
  pack_k<<<1024, 256, 0, stream>>>(edge_index, edge_type, eix, eix_s,
                                   srcte_d, dstte_s);

  // all 3 layers' edge-type tables in one launch (weights-only dependency)
  edge_tables3_k<<<3 * NT, 256, 0, stream>>>(We1, be1, g1, bb1, We2, be2,
                                             Wk, bk, Wm, bm, ketab3, metab3);

  // H0 = gelu(node_emb @ W_lm2gnn + b)
  gemm_k<<<gg, 256, 0, stream>>>(node_emb, W_lm2gnn, b_lm2gnn, nullptr,
                                 nullptr, H0, NN, DIN, DD, 1);

  const float* Xcur = H0;
  for (int l = 0; l < 3; ++l) {
    // fused Q/K/M projections (A-tile staged once)
    gemm3_k<<<gg, 256, 0, stream>>>(Xcur, Wq + (size_t)l * DD * DD, bq + l * DD,
                                    Wk + (size_t)l * 2 * DD * DD,
                                    Wm + (size_t)l * 2 * DD * DD,
                                    Qb, Kb, Mb, NN);

    // fused scores + softmax stats (wave per src; Q row loaded once)
    score2_k<<<(NN + 3) / 4, 256, 0, stream>>>(Qb, Kb, ketab3 + (size_t)l * NT * DD,
                                               offs_s, dstte_s, sbuf, sd);

    // aggregate into Kb (K dead after score2_k)
    aggr2_k<<<(NN + 3) / 4, 256, 0, stream>>>(Mb, metab3 + (size_t)l * NT * DD,
                                              sbuf, sd, cnt, offs, srcte_d, Kb);

    // Xl = relu(bn(aggr@Wp1 + bp1)); X = gelu(Xl@Wp2 + bp2)
    gemm_k<<<gg, 256, 0, stream>>>(Kb, Wp1 + (size_t)l * DD * DD, bp1 + l * DD,
                                   g2 + l * DD, bb2 + l * DD, Qb, NN, DD, DD, 2);
    gemm_k<<<gg, 256, 0, stream>>>(Qb, Wp2 + (size_t)l * DD * DD, bp2 + l * DD,
                                   nullptr, nullptr, Xb, NN, DD, DD, 1);
    Xcur = Xb;
  }

  // hidden = gelu(H0@Wo + bo + X@Wc + bc) — fused K=512 two-segment gemm
  gemm_cat_k<<<gg, 256, 0, stream>>>(H0, Wo, bo, Xb, Wc, bc, Qb, NN);

  emis_k<<<1250, 256, 0, stream>>>(Qb, Wt, bt, em);
  viterbi_k<<<1, 256, 0, stream>>>(em, cstart, cend, ctrans, sv, (int*)d_out);
}

// Round 8
// 2619.645 us; speedup vs baseline: 1.1102x; 1.1102x over previous
//
#include <hip/hip_runtime.h>

// Problem constants (fixed by the reference)
#define NN 20000      // nodes
#define EE 240000     // real edges
#define ETOTAL 260000 // edges + self loops
#define DIN 768
#define DD 256
#define NT 9          // tags
// heads = 4, DH = 64

typedef __attribute__((ext_vector_type(2))) float f32x2;

__device__ __forceinline__ float gelu_f(float x) {
  return 0.5f * x * (1.0f + erff(x * 0.70710678118654752440f));
}

// One Viterbi recurrence step (bitwise-exact). Measured model (r0-r2):
// step cost ~= 62 cyc fixed dependency chain + ~2.9 cyc/instr. Structurally
// minimal for an exact 9-state step; exact time-parallelization ruled out
// (boundary-stitch fp perturbation -> path flips). ~1.1 ms floor; unchanged.
#define VSTEP_CORE(EIN, SIN, SOUT)                                        \
  asm volatile(                                                           \
    "s_nop 2\n\t"                                                         \
    "v_readlane_b32 s84, %[sv], 0\n\t"                                    \
    "v_readlane_b32 s85, %[sv], 1\n\t"                                    \
    "v_readlane_b32 s86, %[sv], 2\n\t"                                    \
    "v_readlane_b32 s87, %[sv], 3\n\t"                                    \
    "v_readlane_b32 s88, %[sv], 4\n\t"                                    \
    "v_readlane_b32 s89, %[sv], 5\n\t"                                    \
    "v_readlane_b32 s90, %[sv], 6\n\t"                                    \
    "v_readlane_b32 s91, %[sv], 7\n\t"                                    \
    "v_readlane_b32 s92, %[sv], 8\n\t"                                    \
    "v_pk_add_f32 v[80:81], s[84:85], %[u01]\n\t"                         \
    "v_pk_add_f32 v[82:83], s[86:87], %[u23]\n\t"                         \
    "v_pk_add_f32 v[84:85], s[88:89], %[u45]\n\t"                         \
    "v_pk_add_f32 v[86:87], s[90:91], %[u67]\n\t"                         \
    "v_add_f32 v88, s92, %[u8]\n\t"                                       \
    "v_max3_f32 v80, v80, v81, v82\n\t"                                   \
    "v_max3_f32 v83, v83, v84, v85\n\t"                                   \
    "v_max3_f32 v86, v86, v87, v88\n\t"                                   \
    "v_max3_f32 v80, v80, v83, v86\n\t"                                   \
    "v_add_f32 %[out], v80, %[e]\n\t"                                     \
    : [out]"=v"(SOUT)                                                     \
    : [sv]"v"(SIN), [e]"v"(EIN),                                          \
      [u01]"v"(tc01), [u23]"v"(tc23), [u45]"v"(tc45), [u67]"v"(tc67),     \
      [u8]"v"(tcol8)                                                      \
    : "s84","s85","s86","s87","s88","s89","s90","s91","s92",              \
      "v80","v81","v82","v83","v84","v85","v86","v87","v88")

// 8 steps; sv layout packs 4 consecutive steps of one lane into one float4
// (sv[(t>>2)*256 + lane*4 + (t&3)]) -> one dwordx4 store per 4 steps.
#define RUN8(E0, E1) do {                                                 \
  float s0, s1, s2, s3, s4, s5, s6, s7;                                   \
  VSTEP_CORE((E0).x, s, s0); VSTEP_CORE((E0).y, s0, s1);                  \
  VSTEP_CORE((E0).z, s1, s2); VSTEP_CORE((E0).w, s2, s3);                 \
  float4 stq0; stq0.x = s0; stq0.y = s1; stq0.z = s2; stq0.w = s3;        \
  *(float4*)svp = stq0;                                                   \
  VSTEP_CORE((E1).x, s3, s4); VSTEP_CORE((E1).y, s4, s5);                 \
  VSTEP_CORE((E1).z, s5, s6); VSTEP_CORE((E1).w, s6, s7);                 \
  float4 stq1; stq1.x = s4; stq1.y = s5; stq1.z = s6; stq1.w = s7;        \
  *(float4*)(svp + 256) = stq1;                                           \
  s = s7; svp += 512;                                                     \
} while (0)

// ---------------- GEMM: C = act(A@B + bias) ----------------
// A: MxK row-major, B: KxN row-major, C: MxN. Requires N%64==0, K%32==0.
// act: 0 = none, 1 = gelu, 2 = bn(g,b) then relu
// 64x64 tile, 4x4/thread, SINGLE-buffered 16KB LDS. This is the empirical
// optimum: 64x128 (r3, grid halved) and double-buffered 32KB LDS + reg
// staging (r6, occupancy cut) BOTH regressed ~+10%. On these small
// grid-limited GEMMs, TLP across co-resident blocks dominates any
// intra-block latency-hiding restructure — do not reduce blocks/CU.
__global__ __launch_bounds__(256) void gemm_k(
    const float* __restrict__ A, const float* __restrict__ B,
    const float* __restrict__ bias,
    const float* __restrict__ bng, const float* __restrict__ bnb,
    float* __restrict__ C, int M, int K, int N, int act)
{
  __shared__ float As[32][64];   // transposed A tile: As[k][m]
  __shared__ float Bs[32][64];   // Bs[k][n]
  const int tid = threadIdx.x;
  const int tx = tid & 15, ty = tid >> 4;
  const int m0 = blockIdx.y * 64, n0 = blockIdx.x * 64;
  float acc[4][4];
#pragma unroll
  for (int i = 0; i < 4; ++i)
#pragma unroll
    for (int j = 0; j < 4; ++j) acc[i][j] = 0.f;

  for (int kk = 0; kk < K; kk += 32) {
#pragma unroll
    for (int L = tid; L < 512; L += 256) {   // A tile: 64 rows x 8 float4
      int r = L >> 3, c4 = L & 7;
      int gm = m0 + r;
      float4 v = make_float4(0.f, 0.f, 0.f, 0.f);
      if (gm < M) v = *(const float4*)(A + (size_t)gm * K + kk + c4 * 4);
      As[c4 * 4 + 0][r] = v.x; As[c4 * 4 + 1][r] = v.y;
      As[c4 * 4 + 2][r] = v.z; As[c4 * 4 + 3][r] = v.w;
    }
#pragma unroll
    for (int L = tid; L < 512; L += 256) {   // B tile: 32 rows x 16 float4
      int r = L >> 4, c4 = L & 15;
      *(float4*)&Bs[r][c4 * 4] = *(const float4*)(B + (size_t)(kk + r) * N + n0 + c4 * 4);
    }
    __syncthreads();
#pragma unroll
    for (int k = 0; k < 32; ++k) {
      float a[4], b[4];
      *(float4*)a = *(const float4*)&As[k][ty * 4];
      *(float4*)b = *(const float4*)&Bs[k][tx * 4];
#pragma unroll
      for (int i = 0; i < 4; ++i)
#pragma unroll
        for (int j = 0; j < 4; ++j) acc[i][j] += a[i] * b[j];
    }
    __syncthreads();
  }
  const float bnc = 0.99999500003749968752f;  // 1/sqrt(1+1e-5)
#pragma unroll
  for (int i = 0; i < 4; ++i) {
    int gm = m0 + ty * 4 + i;
    if (gm >= M) continue;
    float o[4];
#pragma unroll
    for (int j = 0; j < 4; ++j) {
      int n = n0 + tx * 4 + j;
      float x = acc[i][j];
      if (bias) x += bias[n];
      if (act == 1) x = gelu_f(x);
      else if (act == 2) { x = x * (bng[n] * bnc) + bnb[n]; x = fmaxf(x, 0.f); }
      o[j] = x;
    }
    *(float4*)(C + (size_t)gm * N + n0 + tx * 4) = *(const float4*)o;
  }
}

// ---------------- fused Q/K/M projections (shared A, 3 B's) ----------------
// C0 = A@B0 + bias0 ; C1 = A@B1 ; C2 = A@B2. K = N = 256 fixed.
__global__ __launch_bounds__(256) void gemm3_k(
    const float* __restrict__ A, const float* __restrict__ B0,
    const float* __restrict__ bias0, const float* __restrict__ B1,
    const float* __restrict__ B2, float* __restrict__ C0,
    float* __restrict__ C1, float* __restrict__ C2, int M)
{
  __shared__ float As[32][64];
  __shared__ float Bs[3][32][64];
  const int tid = threadIdx.x;
  const int tx = tid & 15, ty = tid >> 4;
  const int m0 = blockIdx.y * 64, n0 = blockIdx.x * 64;
  float acc0[4][4], acc1[4][4], acc2[4][4];
#pragma unroll
  for (int i = 0; i < 4; ++i)
#pragma unroll
    for (int j = 0; j < 4; ++j) { acc0[i][j] = 0.f; acc1[i][j] = 0.f; acc2[i][j] = 0.f; }

  for (int kk = 0; kk < DD; kk += 32) {
#pragma unroll
    for (int L = tid; L < 512; L += 256) {   // A tile: 64 rows x 8 float4
      int r = L >> 3, c4 = L & 7;
      int gm = m0 + r;
      float4 v = make_float4(0.f, 0.f, 0.f, 0.f);
      if (gm < M) v = *(const float4*)(A + (size_t)gm * DD + kk + c4 * 4);
      As[c4 * 4 + 0][r] = v.x; As[c4 * 4 + 1][r] = v.y;
      As[c4 * 4 + 2][r] = v.z; As[c4 * 4 + 3][r] = v.w;
    }
#pragma unroll
    for (int L = tid; L < 1536; L += 256) {  // 3 B tiles: 32 rows x 16 float4
      int which = L >> 9, r = (L >> 4) & 31, c4 = L & 15;
      const float* Bp = (which == 0) ? B0 : (which == 1) ? B1 : B2;
      *(float4*)&Bs[which][r][c4 * 4] =
          *(const float4*)(Bp + (size_t)(kk + r) * DD + n0 + c4 * 4);
    }
    __syncthreads();
#pragma unroll
    for (int k = 0; k < 32; ++k) {
      float a[4], b0[4], b1[4], b2[4];
      *(float4*)a = *(const float4*)&As[k][ty * 4];
      *(float4*)b0 = *(const float4*)&Bs[0][k][tx * 4];
      *(float4*)b1 = *(const float4*)&Bs[1][k][tx * 4];
      *(float4*)b2 = *(const float4*)&Bs[2][k][tx * 4];
#pragma unroll
      for (int i = 0; i < 4; ++i)
#pragma unroll
        for (int j = 0; j < 4; ++j) {
          acc0[i][j] += a[i] * b0[j];
          acc1[i][j] += a[i] * b1[j];
          acc2[i][j] += a[i] * b2[j];
        }
    }
    __syncthreads();
  }
#pragma unroll
  for (int i = 0; i < 4; ++i) {
    int gm = m0 + ty * 4 + i;
    if (gm >= M) continue;
    float o0[4], o1[4], o2[4];
#pragma unroll
    for (int j = 0; j < 4; ++j) {
      int n = n0 + tx * 4 + j;
      o0[j] = acc0[i][j] + bias0[n];
      o1[j] = acc1[i][j];
      o2[j] = acc2[i][j];
    }
    *(float4*)(C0 + (size_t)gm * DD + n0 + tx * 4) = *(const float4*)o0;
    *(float4*)(C1 + (size_t)gm * DD + n0 + tx * 4) = *(const float4*)o1;
    *(float4*)(C2 + (size_t)gm * DD + n0 + tx * 4) = *(const float4*)o2;
  }
}

// ---------------- fused two-segment GEMM: C = gelu(A1@B1 + A2@B2 + b1 + b2) -
// K = 256 per segment, N = 256 fixed. 64x64 tile, single-buffered (see gemm_k).
__global__ __launch_bounds__(256) void gemm_cat_k(
    const float* __restrict__ A1, const float* __restrict__ B1,
    const float* __restrict__ bias1, const float* __restrict__ A2,
    const float* __restrict__ B2, const float* __restrict__ bias2,
    float* __restrict__ C, int M)
{
  __shared__ float As[32][64];
  __shared__ float Bs[32][64];
  const int tid = threadIdx.x;
  const int tx = tid & 15, ty = tid >> 4;
  const int m0 = blockIdx.y * 64, n0 = blockIdx.x * 64;
  float acc[4][4];
#pragma unroll
  for (int i = 0; i < 4; ++i)
#pragma unroll
    for (int j = 0; j < 4; ++j) acc[i][j] = 0.f;

  for (int kk = 0; kk < 2 * DD; kk += 32) {
    const float* Ap = (kk < DD) ? A1 : A2;
    const float* Bp = (kk < DD) ? B1 : B2;
    const int ko = kk & (DD - 1);
#pragma unroll
    for (int L = tid; L < 512; L += 256) {
      int r = L >> 3, c4 = L & 7;
      int gm = m0 + r;
      float4 v = make_float4(0.f, 0.f, 0.f, 0.f);
      if (gm < M) v = *(const float4*)(Ap + (size_t)gm * DD + ko + c4 * 4);
      As[c4 * 4 + 0][r] = v.x; As[c4 * 4 + 1][r] = v.y;
      As[c4 * 4 + 2][r] = v.z; As[c4 * 4 + 3][r] = v.w;
    }
#pragma unroll
    for (int L = tid; L < 512; L += 256) {
      int r = L >> 4, c4 = L & 15;
      *(float4*)&Bs[r][c4 * 4] = *(const float4*)(Bp + (size_t)(ko + r) * DD + n0 + c4 * 4);
    }
    __syncthreads();
#pragma unroll
    for (int k = 0; k < 32; ++k) {
      float a[4], b[4];
      *(float4*)a = *(const float4*)&As[k][ty * 4];
      *(float4*)b = *(const float4*)&Bs[k][tx * 4];
#pragma unroll
      for (int i = 0; i < 4; ++i)
#pragma unroll
        for (int j = 0; j < 4; ++j) acc[i][j] += a[i] * b[j];
    }
    __syncthreads();
  }
#pragma unroll
  for (int i = 0; i < 4; ++i) {
    int gm = m0 + ty * 4 + i;
    if (gm >= M) continue;
    float o[4];
#pragma unroll
    for (int j = 0; j < 4; ++j) {
      int n = n0 + tx * 4 + j;
      o[j] = gelu_f(acc[i][j] + bias1[n] + bias2[n]);
    }
    *(float4*)(C + (size_t)gm * DD + n0 + tx * 4) = *(const float4*)o;
  }
}

// ---------------- per-layer edge-type tables, all 3 layers batched ---------
// 27 blocks (layer = blockIdx/NT, type = blockIdx%NT); weights-only
// dependency -> hoisted out of the layer loop (one launch instead of three).
__global__ __launch_bounds__(256) void edge_tables3_k(
    const float* __restrict__ We1, const float* __restrict__ be1,
    const float* __restrict__ g1, const float* __restrict__ bb1,
    const float* __restrict__ We2, const float* __restrict__ be2,
    const float* __restrict__ Wk, const float* __restrict__ bk,
    const float* __restrict__ Wm, const float* __restrict__ bm,
    float* __restrict__ ketab3, float* __restrict__ metab3)
{
  __shared__ float r_s[DD];
  __shared__ float e_s[DD];
  const int l = blockIdx.x / NT, t = blockIdx.x - l * NT, d = threadIdx.x;
  const float* We1l = We1 + (size_t)l * NT * DD;
  const float* We2l = We2 + (size_t)l * DD * DD;
  const float* WkEl = Wk + (size_t)l * 2 * DD * DD + DD * DD;
  const float* WmEl = Wm + (size_t)l * 2 * DD * DD + DD * DD;
  const float bnc = 0.99999500003749968752f;
  float pre = We1l[t * DD + d] + be1[l * DD + d];
  float bnv = pre * (g1[l * DD + d] * bnc) + bb1[l * DD + d];
  r_s[d] = fmaxf(bnv, 0.f);
  __syncthreads();
  float acc = 0.f;
  for (int c = 0; c < DD; ++c) acc += r_s[c] * We2l[c * DD + d];
  e_s[d] = acc + be2[l * DD + d];
  __syncthreads();
  float ka = 0.f, ma = 0.f;
  for (int c = 0; c < DD; ++c) {
    float ec = e_s[c];
    ka += ec * WkEl[c * DD + d];
    ma += ec * WmEl[c * DD + d];
  }
  ketab3[(size_t)l * NT * DD + t * DD + d] = ka + bk[l * DD + d];
  metab3[(size_t)l * NT * DD + t * DD + d] = ma + bm[l * DD + d];
}

// ---------------- degree counts ----------------
__global__ void deg_k(const int* __restrict__ ei, int* __restrict__ cnt,
                      int* __restrict__ cnt_d)
{
  for (int e = blockIdx.x * blockDim.x + threadIdx.x; e < EE; e += gridDim.x * blockDim.x) {
    atomicAdd(&cnt[ei[e]], 1);        // src out-degree (real edges)
    atomicAdd(&cnt_d[ei[EE + e]], 1); // dst in-degree (real edges)
  }
}

// ---------------- exclusive scan (single block, generic input) -------------
__global__ __launch_bounds__(256) void scan_k(const int* __restrict__ c,
                                              int* __restrict__ offs)
{
  __shared__ int part[257];
  const int tid = threadIdx.x;
  const int CH = (NN + 255) / 256;
  int a = tid * CH, b = a + CH; if (b > NN) b = NN;
  int s = 0;
  for (int i = a; i < b; ++i) s += c[i];
  part[tid] = s;
  __syncthreads();
  if (tid == 0) {
    int r = 0;
    for (int i = 0; i < 256; ++i) { int v = part[i]; part[i] = r; r += v; }
    part[256] = r;
  }
  __syncthreads();
  int r = part[tid];
  for (int i = a; i < b; ++i) { offs[i] = r; r += c[i]; }
  if (tid == 255) offs[NN] = part[256];
}

// ---------------- CSR fill (generic key array) ----------------
__global__ void fill_k(const int* __restrict__ key, const int* __restrict__ offs,
                       int* __restrict__ fc, int* __restrict__ eix)
{
  for (int e = blockIdx.x * blockDim.x + threadIdx.x; e < EE; e += gridDim.x * blockDim.x) {
    int d = key[e];
    int p = offs[d] + atomicAdd(&fc[d], 1);
    eix[p] = e;
  }
}

// ---------------- pack CSR payloads: {other-node, (e<<4)|type} -------------
// Flattens the eix->ei->et dependent-load chains in score2/aggr2 to a single
// 8B load per edge (e < 2^18, t < 16).
__global__ void pack_k(const int* __restrict__ ei, const int* __restrict__ et,
                       const int* __restrict__ eix, const int* __restrict__ eix_s,
                       int2* __restrict__ srcte_d, int2* __restrict__ dstte_s)
{
  for (int o = blockIdx.x * blockDim.x + threadIdx.x; o < EE; o += gridDim.x * blockDim.x) {
    int e = eix[o];                       // dst-CSR slot o
    srcte_d[o] = make_int2(ei[e], (e << 4) | et[e]);
    int e2 = eix_s[o];                    // src-CSR slot o
    dstte_s[o] = make_int2(ei[EE + e2], (e2 << 4) | et[e2]);
  }
}

// ---------------- fused scores + softmax stats (wave per src) --------------
// Q row loaded ONCE per src. Dot expression q·(k+ke), shuffle order, and
// *0.125 are IDENTICAL to the original score_k -> sbuf and the segment max
// are bitwise unchanged. The denominator uses an online running-max sum
// (order perturbation ~1e-7 — empirically validated by r4's atomic->tree
// den change, path bit-identical).
__global__ __launch_bounds__(256) void score2_k(
    const float* __restrict__ Q, const float* __restrict__ Kn,
    const float* __restrict__ ketab, const int* __restrict__ offs_s,
    const int2* __restrict__ dstte_s, float* __restrict__ sbuf,
    float2* __restrict__ sd)
{
  __shared__ float ke_s[NT * DD];
  for (int i = threadIdx.x; i < NT * DD; i += 256) ke_s[i] = ketab[i];
  __syncthreads();
  const int lane = threadIdx.x & 63, wave = threadIdx.x >> 6;
  const int h = lane >> 4, sl = lane & 15;
  const float4* Q4 = (const float4*)Q;
  const float4* K4 = (const float4*)Kn;
  int src = blockIdx.x * 4 + wave;
  if (src >= NN) return;
  float4 q = Q4[src * 64 + lane];
  float mx, sum;
  {
    // self-loop (edge id EE+src, type NT-1), k row = K[src]
    float4 k = K4[src * 64 + lane];
    float4 ke = *(const float4*)(ke_s + (NT - 1) * DD + lane * 4);
    float p = q.x * (k.x + ke.x) + q.y * (k.y + ke.y) +
              q.z * (k.z + ke.z) + q.w * (k.w + ke.w);
    p += __shfl_xor(p, 8); p += __shfl_xor(p, 4);
    p += __shfl_xor(p, 2); p += __shfl_xor(p, 1);
    float se = p * 0.125f;
    if (sl == 0) sbuf[(EE + src) * 4 + h] = se;
    mx = se; sum = 1.0f;                 // expf(se-se)=1 exactly
  }
  int o1 = offs_s[src + 1];
  for (int o = offs_s[src]; o < o1; ++o) {
    int2 dt = dstte_s[o];
    int dst = dt.x, e = dt.y >> 4, t = dt.y & 15;
    float4 k = K4[dst * 64 + lane];
    float4 ke = *(const float4*)(ke_s + t * DD + lane * 4);
    float p = q.x * (k.x + ke.x) + q.y * (k.y + ke.y) +
              q.z * (k.z + ke.z) + q.w * (k.w + ke.w);
    p += __shfl_xor(p, 8); p += __shfl_xor(p, 4);
    p += __shfl_xor(p, 2); p += __shfl_xor(p, 1);
    float se = p * 0.125f;
    if (sl == 0) sbuf[e * 4 + h] = se;
    float nm = fmaxf(mx, se);            // final mx bitwise = old atomicMax
    sum = sum * expf(mx - nm) + expf(se - nm);  // exp(0)=1 exact
    mx = nm;
  }
  if (sl == 0) sd[src * 4 + h] = make_float2(mx, sum);
}

// ---------------- pass C: atomic-free aggregation (wave per dst) -----------
// alpha computed inline from raw scores + packed {max,den}; per-edge payload
// from the packed dst-CSR (single 8B load, no eix->ei->et chain).
__global__ __launch_bounds__(256) void aggr2_k(
    const float* __restrict__ Mn, const float* __restrict__ metab,
    const float* __restrict__ sbuf, const float2* __restrict__ sd,
    const int* __restrict__ cnt, const int* __restrict__ offs,
    const int2* __restrict__ srcte_d, float* __restrict__ aggr)
{
  __shared__ float me_s[NT * DD];
  for (int i = threadIdx.x; i < NT * DD; i += 256) me_s[i] = metab[i];
  __syncthreads();
  const int lane = threadIdx.x & 63, wave = threadIdx.x >> 6;
  const int h = lane >> 4;
  const float4* M4 = (const float4*)Mn;
  int dst = blockIdx.x * 4 + wave;
  if (dst >= NN) return;
  float4 acc;
  {
    // self-loop (edge id EE+dst, type NT-1)
    float2 sdv = sd[dst * 4 + h];
    float ex = expf(sbuf[(EE + dst) * 4 + h] - sdv.x);
    float alpha = ex / (sdv.y + 1e-16f) * (float)(cnt[dst] + 1);
    float4 m = M4[dst * 64 + lane];
    float4 me = *(const float4*)(me_s + (NT - 1) * DD + lane * 4);
    acc.x = (m.x + me.x) * alpha; acc.y = (m.y + me.y) * alpha;
    acc.z = (m.z + me.z) * alpha; acc.w = (m.w + me.w) * alpha;
  }
  int o1 = offs[dst + 1];
  for (int o = offs[dst]; o < o1; ++o) {
    int2 st = srcte_d[o];
    int src = st.x, e = st.y >> 4, t = st.y & 15;
    float2 sdv = sd[src * 4 + h];
    float ex = expf(sbuf[e * 4 + h] - sdv.x);
    float alpha = ex / (sdv.y + 1e-16f) * (float)(cnt[src] + 1);
    float4 m = M4[src * 64 + lane];
    float4 me = *(const float4*)(me_s + t * DD + lane * 4);
    acc.x += (m.x + me.x) * alpha; acc.y += (m.y + me.y) * alpha;
    acc.z += (m.z + me.z) * alpha; acc.w += (m.w + me.w) * alpha;
  }
  ((float4*)aggr)[dst * 64 + lane] = acc;
}

// ---------------- emissions: em = hidden @ Wt + bt  (256 -> 9) -------------
__global__ __launch_bounds__(256) void emis_k(
    const float* __restrict__ hidden, const float* __restrict__ Wt,
    const float* __restrict__ bt, float* __restrict__ em)
{
  __shared__ float wt_s[DD * NT];
  for (int i = threadIdx.x; i < DD * NT; i += 256) wt_s[i] = Wt[i];
  __syncthreads();
  const int lane = threadIdx.x & 63, wave = threadIdx.x >> 6;
  const float4* H4 = (const float4*)hidden;
  for (int n = blockIdx.x * 4 + wave; n < NN; n += gridDim.x * 4) {
    float4 h = H4[n * 64 + lane];
    const float* w0 = wt_s + (lane * 4) * NT;
    float p[NT];
#pragma unroll
    for (int t = 0; t < NT; ++t)
      p[t] = h.x * w0[t] + h.y * w0[NT + t] + h.z * w0[2 * NT + t] + h.w * w0[3 * NT + t];
#pragma unroll
    for (int m = 32; m >= 1; m >>= 1)
#pragma unroll
      for (int t = 0; t < NT; ++t) p[t] += __shfl_xor(p[t], m);
    if (lane == 0) {
#pragma unroll
      for (int t = 0; t < NT; ++t) em[n * NT + t] = p[t] + bt[t];
    }
  }
}

// ---------------- Viterbi decode (single block) ----------------------------
// Forward scan: wave0, lanes replicate states j=min(lane&15,8). Recurrence =
// VSTEP_CORE asm (readlane into SGPR pairs + 4 pk_add + exact max3 tree ->
// bitwise identical). Emissions staged TRANSPOSED in LDS (embufT[j][t],
// padded row stride 524): one ds_read_b128 delivers 4 steps; double-buffered
// one 8-step group ahead. Score rows stored quad-packed:
// sv[(t>>2)*256 + lane*4 + (t&3)] -> one dwordx4 store per 4 steps.
// Backpointers recomputed bitwise-exactly in the parallel backtrack
// (first-index tie rule = jnp.argmax).
__global__ __launch_bounds__(256) void viterbi_k(
    const float* __restrict__ em, const float* __restrict__ cstart,
    const float* __restrict__ cend, const float* __restrict__ ctrans,
    float* __restrict__ sv, int* __restrict__ outp)
{
  const int VCS = 512;
  const int ST = VCS + 12;        // 524 floats: 524%32=12 -> 9 rows spread banks
  const int NCH = (NN + VCS - 1) / VCS;
  __shared__ float embufT[2][NT][VCS + 12];
  __shared__ float trT[NT * 16];              // trT[j*16+i] = trans[i][j]
  __shared__ float scf[NT];
  __shared__ unsigned char fmaps[256][NT];
  __shared__ unsigned char ends_s[256];
  __shared__ int last_s;
  const int tid = threadIdx.x, lane = tid & 63, wave = tid >> 6;
  const int jl = min(lane & 15, NT - 1);

  for (int i = tid; i < VCS * NT; i += 256) {   // chunk 0, transposed
    int t = i / NT, j = i - t * NT;
    embufT[0][j][t] = em[i];
  }
  if (tid < NT * NT) trT[(tid % NT) * 16 + (tid / NT)] = ctrans[tid];
  __syncthreads();

  f32x2 tc01, tc23, tc45, tc67;   // tcol[i] = trans[i][jl], packed in pairs
  float tcol8 = 0.f;
  float s = 0.f;
  if (wave == 0) {
    tc01[0] = ctrans[0 * NT + jl]; tc01[1] = ctrans[1 * NT + jl];
    tc23[0] = ctrans[2 * NT + jl]; tc23[1] = ctrans[3 * NT + jl];
    tc45[0] = ctrans[4 * NT + jl]; tc45[1] = ctrans[5 * NT + jl];
    tc67[0] = ctrans[6 * NT + jl]; tc67[1] = ctrans[7 * NT + jl];
    tcol8   = ctrans[8 * NT + jl];
    s = cstart[jl] + embufT[0][jl][0];
    sv[lane * 4] = s;             // row t=0: quad 0, slot 0
  }

  for (int c = 0; c < NCH; ++c) {
    if (wave > 0) {
      if (c + 1 < NCH) {
        int base = (c + 1) * VCS * NT;
        int n2 = VCS * NT;
        if (base + n2 > NN * NT) n2 = NN * NT - base;
        float* dstb = &embufT[(c + 1) & 1][0][0];
        for (int i = tid - 64; i < n2; i += 192) {
          int t = i / NT, j = i - t * NT;
          dstb[j * ST + t] = em[base + i];
        }
      }
    } else {
      const float* ebT = &embufT[c & 1][0][0] + (size_t)jl * ST;
      int tbeg = (c == 0) ? 1 : c * VCS;
      int tend = (c + 1) * VCS; if (tend > NN) tend = NN;
      int off = tbeg - c * VCS;
      int nsteps = tend - tbeg;
      // scalar head: align t to a multiple of 8
      int pre = (8 - (tbeg & 7)) & 7; if (pre > nsteps) pre = nsteps;
      for (int i = 0; i < pre; ++i) {
        int t = tbeg + i;
        float e0 = ebT[off + i];
        float so;
        VSTEP_CORE(e0, s, so);
        s = so;
        sv[((size_t)t >> 2) * 256 + lane * 4 + (t & 3)] = s;
      }
      int rem = nsteps - pre;
      int ngr = rem >> 3;
      int tof = off + pre;                     // 16B-aligned (0 or 8)
      float* svp = sv + ((size_t)(tbeg + pre) >> 2) * 256 + lane * 4;
      if (ngr > 0) {
        float4 eA0 = *(const float4*)&ebT[tof];
        float4 eA1 = *(const float4*)&ebT[tof + 4];
        float4 eB0, eB1;
        int g = 0;
        while (g + 2 <= ngr) {
          eB0 = *(const float4*)&ebT[tof + (g + 1) * 8];
          eB1 = *(const float4*)&ebT[tof + (g + 1) * 8 + 4];
          RUN8(eA0, eA1);
          eA0 = *(const float4*)&ebT[tof + (g + 2) * 8];     // pad overread ok
          eA1 = *(const float4*)&ebT[tof + (g + 2) * 8 + 4];
          RUN8(eB0, eB1);
          g += 2;
        }
        if (g < ngr) RUN8(eA0, eA1);
      }
      // scalar tail (rem % 8 steps; 0 for this problem size but kept generic)
      for (int i = pre + (ngr << 3); i < nsteps; ++i) {
        int t = tbeg + i;
        float e0 = ebT[off + i];
        float so;
        VSTEP_CORE(e0, s, so);
        s = so;
        sv[((size_t)t >> 2) * 256 + lane * 4 + (t & 3)] = s;
      }
    }
    __syncthreads();
  }

  if (wave == 0 && lane < NT) scf[lane] = s + cend[lane];
  __syncthreads();
  if (tid == 0) {
    float bv = scf[0]; int bi = 0;
    for (int j = 1; j < NT; ++j) if (scf[j] > bv) { bv = scf[j]; bi = j; }
    last_s = bi;
  }
  __syncthreads();

  // backtrack: per-range end->start maps via exact bp recomputation
  // sv row t, state i lives at sv[(t>>2)*256 + i*4 + (t&3)]
  const int RL = 79;
  int a = 1 + tid * RL;
  int b = a + RL; if (b > NN) b = NN;
  bool active = (a < NN);
  if (active) {
    int x[NT];
#pragma unroll
    for (int j = 0; j < NT; ++j) x[j] = j;
    for (int t = b - 1; t >= a; --t) {
      const float* sp = sv + ((size_t)(t - 1) >> 2) * 256 + ((t - 1) & 3);
      float sr[NT];
#pragma unroll
      for (int i = 0; i < NT; ++i) sr[i] = sp[i * 4];
#pragma unroll
      for (int j = 0; j < NT; ++j) {
        const float* tcx = trT + x[j] * 16;
        float bv = sr[0] + tcx[0]; int bi = 0;
#pragma unroll
        for (int i = 1; i < NT; ++i) {
          float cv = sr[i] + tcx[i];
          if (cv > bv) { bv = cv; bi = i; }
        }
        x[j] = bi;
      }
    }
#pragma unroll
    for (int j = 0; j < NT; ++j) fmaps[tid][j] = (unsigned char)x[j];
  }
  __syncthreads();
  if (tid == 0) {
    int x = last_s;
    for (int k = 255; k >= 0; --k) {
      ends_s[k] = (unsigned char)x;
      int ak = 1 + k * RL;
      if (ak < NN) x = fmaps[k][x];
    }
  }
  __syncthreads();
  if (active) {
    int x = ends_s[tid];
    outp[b - 1] = x;
    for (int t = b - 1; t >= a; --t) {
      const float* sp = sv + ((size_t)(t - 1) >> 2) * 256 + ((t - 1) & 3);
      const float* tcx = trT + x * 16;
      float bv = sp[0] + tcx[0]; int bi = 0;
#pragma unroll
      for (int i = 1; i < NT; ++i) {
        float cv = sp[i * 4] + tcx[i];
        if (cv > bv) { bv = cv; bi = i; }
      }
      x = bi;
      outp[t - 1] = x;
    }
  }
}

// ---------------------------------------------------------------------------
extern "C" void kernel_launch(void* const* d_in, const int* in_sizes, int n_in,
                              void* d_out, int out_size, void* d_ws, size_t ws_size,
                              hipStream_t stream)
{
  const float* node_emb = (const float*)d_in[0];
  const int* edge_index = (const int*)d_in[1];
  const int* edge_type = (const int*)d_in[2];
  // d_in[3] = tag_gt (unused by reference)
  const float* W_lm2gnn = (const float*)d_in[4];
  const float* b_lm2gnn = (const float*)d_in[5];
  const float* We1 = (const float*)d_in[6];
  const float* be1 = (const float*)d_in[7];
  const float* g1 = (const float*)d_in[8];
  const float* bb1 = (const float*)d_in[9];
  const float* We2 = (const float*)d_in[10];
  const float* be2 = (const float*)d_in[11];
  const float* Wq = (const float*)d_in[12];
  const float* bq = (const float*)d_in[13];
  const float* Wk = (const float*)d_in[14];
  const float* bk = (const float*)d_in[15];
  const float* Wm = (const float*)d_in[16];
  const float* bm = (const float*)d_in[17];
  const float* Wp1 = (const float*)d_in[18];
  const float* bp1 = (const float*)d_in[19];
  const float* g2 = (const float*)d_in[20];
  const float* bb2 = (const float*)d_in[21];
  const float* Wp2 = (const float*)d_in[22];
  const float* bp2 = (const float*)d_in[23];
  const float* Wo = (const float*)d_in[24];
  const float* bo = (const float*)d_in[25];
  const float* Wc = (const float*)d_in[26];
  const float* bc = (const float*)d_in[27];
  const float* Wt = (const float*)d_in[28];
  const float* bt = (const float*)d_in[29];
  const float* cstart = (const float*)d_in[30];
  const float* cend = (const float*)d_in[31];
  const float* ctrans = (const float*)d_in[32];

  // Workspace layout: 5 big node buffers + small region.
  const size_t NB = (size_t)NN * DD * sizeof(float); // 20,480,000
  char* w = (char*)d_ws;
  float* H0 = (float*)(w + 0 * NB);
  float* Xb = (float*)(w + 1 * NB);
  float* Qb = (float*)(w + 2 * NB);   // Q, then Xl, then hidden
  float* Kb = (float*)(w + 3 * NB);   // K, then aggr
  float* Mb = (float*)(w + 4 * NB);   // M
  char* sm = w + 5 * NB;
  size_t smo = 0;
  auto alloc = [&](size_t bytes) { char* p = sm + smo; smo += (bytes + 255) & ~255ull; return p; };
  float* sbuf = (float*)alloc((size_t)ETOTAL * 4 * 4);
  // zeroed-together region: cnt, cnt_d, offs, fc, offs_s, fc_s
  int* cnt = (int*)alloc((size_t)NN * 4);
  int* cnt_d = (int*)alloc((size_t)NN * 4);
  int* offs = (int*)alloc((size_t)(NN + 1) * 4);
  int* fc = (int*)alloc((size_t)NN * 4);
  int* offs_s = (int*)alloc((size_t)(NN + 1) * 4);
  int* fc_s = (int*)alloc((size_t)NN * 4);
  int* eix = (int*)alloc((size_t)EE * 4);     // dst-CSR edge ids
  int* eix_s = (int*)alloc((size_t)EE * 4);   // src-CSR edge ids
  int2* srcte_d = (int2*)alloc((size_t)EE * 8);  // packed dst-CSR payload
  int2* dstte_s = (int2*)alloc((size_t)EE * 8);  // packed src-CSR payload
  float2* sd = (float2*)alloc((size_t)NN * 4 * 8);  // packed {smax, den}
  float* ketab3 = (float*)alloc((size_t)3 * NT * DD * 4);
  float* metab3 = (float*)alloc((size_t)3 * NT * DD * 4);
  float* em = (float*)alloc((size_t)NN * NT * 4);
  float* sv = (float*)alloc(((size_t)NN * 64 + 256) * 4);  // quad-packed score rows
  const size_t needed = 5 * NB + smo;
  if (ws_size < needed) return;  // fail visibly rather than corrupt

  dim3 gg(DD / 64, (NN + 63) / 64);

  // degree counts + dst-CSR + src-CSR + packed payloads (structure constant)
  hipMemsetAsync(cnt, 0, (size_t)((char*)eix - (char*)cnt), stream);
  deg_k<<<1024, 256, 0, stream>>>(edge_index, cnt, cnt_d);
  scan_k<<<1, 256, 0, stream>>>(cnt_d, offs);
  scan_k<<<1, 256, 0, stream>>>(cnt, offs_s);
  fill_k<<<1024, 256, 0, stream>>>(edge_index + EE, offs, fc, eix);    // by dst
  fill_k<<<1024, 256, 0, stream>>>(edge_index, offs_s, fc_s, eix_s);   // by src
  pack_k<<<1024, 256, 0, stream>>>(edge_index, edge_type, eix, eix_s,
                                   srcte_d, dstte_s);

  // all 3 layers' edge-type tables in one launch (weights-only dependency)
  edge_tables3_k<<<3 * NT, 256, 0, stream>>>(We1, be1, g1, bb1, We2, be2,
                                             Wk, bk, Wm, bm, ketab3, metab3);

  // H0 = gelu(node_emb @ W_lm2gnn + b)
  gemm_k<<<gg, 256, 0, stream>>>(node_emb, W_lm2gnn, b_lm2gnn, nullptr,
                                 nullptr, H0, NN, DIN, DD, 1);

  const float* Xcur = H0;
  for (int l = 0; l < 3; ++l) {
    // fused Q/K/M projections (A-tile staged once)
    gemm3_k<<<gg, 256, 0, stream>>>(Xcur, Wq + (size_t)l * DD * DD, bq + l * DD,
                                    Wk + (size_t)l * 2 * DD * DD,
                                    Wm + (size_t)l * 2 * DD * DD,
                                    Qb, Kb, Mb, NN);

    // fused scores + softmax stats (wave per src; Q row loaded once)
    score2_k<<<(NN + 3) / 4, 256, 0, stream>>>(Qb, Kb, ketab3 + (size_t)l * NT * DD,
                                               offs_s, dstte_s, sbuf, sd);

    // aggregate into Kb (K dead after score2_k)
    aggr2_k<<<(NN + 3) / 4, 256, 0, stream>>>(Mb, metab3 + (size_t)l * NT * DD,
                                              sbuf, sd, cnt, offs, srcte_d, Kb);

    // Xl = relu(bn(aggr@Wp1 + bp1)); X = gelu(Xl@Wp2 + bp2)
    gemm_k<<<gg, 256, 0, stream>>>(Kb, Wp1 + (size_t)l * DD * DD, bp1 + l * DD,
                                   g2 + l * DD, bb2 + l * DD, Qb, NN, DD, DD, 2);
    gemm_k<<<gg, 256, 0, stream>>>(Qb, Wp2 + (size_t)l * DD * DD, bp2 + l * DD,
                                   nullptr, nullptr, Xb, NN, DD, DD, 1);
    Xcur = Xb;
  }

  // hidden = gelu(H0@Wo + bo + X@Wc + bc) — fused K=512 two-segment gemm
  gemm_cat_k<<<gg, 256, 0, stream>>>(H0, Wo, bo, Xb, Wc, bc, Qb, NN);

  emis_k<<<1250, 256, 0, stream>>>(Qb, Wt, bt, em);
  viterbi_k<<<1, 256, 0, stream>>>(em, cstart, cend, ctrans, sv, (int*)d_out);
}